// Round 4
// baseline (3825.109 us; speedup 1.0000x reference)
//
#include <hip/hip_runtime.h>
#include <hip/hip_bf16.h>

#define TSEQ 1024
#define NB   128
#define HID  128
#define QDIM 16

// 16 fused fwd+bwd pairs per block (16 waves = 1024 threads) -> 4 waves/SIMD
// co-resident on each of the 4 SIMDs: SMT fills dependency-stall slots.
#define PAIRS_PER_BLOCK 16

typedef unsigned int  u32;
typedef unsigned short u16;
typedef float f32x2 __attribute__((ext_vector_type(2)));

// ---------------- cross-lane helpers (wave64) ----------------

template<int CTRL>
__device__ __forceinline__ int dpp_i(int x) {
  return __builtin_amdgcn_update_dpp(0, x, CTRL, 0xF, 0xF, true);
}
template<int CTRL>
__device__ __forceinline__ float dpp_f(float x) {
  return __int_as_float(dpp_i<CTRL>(__float_as_int(x)));
}

#ifdef __has_builtin
#if __has_builtin(__builtin_amdgcn_permlane16_swap) && __has_builtin(__builtin_amdgcn_permlane32_swap)
#define HAS_PLS 1
#endif
#endif
#ifndef HAS_PLS
#define HAS_PLS 0
#endif

__device__ __forceinline__ float pls16_sum(float x) {
#if HAS_PLS
  auto r = __builtin_amdgcn_permlane16_swap(__float_as_uint(x), __float_as_uint(x), false, false);
  return __uint_as_float(r[0]) + __uint_as_float(r[1]);
#else
  return x + __shfl_xor(x, 16, 64);
#endif
}
__device__ __forceinline__ float pls32_sum(float x) {
#if HAS_PLS
  auto r = __builtin_amdgcn_permlane32_swap(__float_as_uint(x), __float_as_uint(x), false, false);
  return __uint_as_float(r[0]) + __uint_as_float(r[1]);
#else
  return x + __shfl_xor(x, 32, 64);
#endif
}
__device__ __forceinline__ float pls32_other(float x) { return pls32_sum(x) - x; }

__device__ __forceinline__ float rcpf(float x) { return __builtin_amdgcn_rcpf(x); }

__device__ __forceinline__ float ex2(float x) {
#if defined(__has_builtin)
#if __has_builtin(__builtin_amdgcn_exp2f)
  return __builtin_amdgcn_exp2f(x);
#else
  return exp2f(x);
#endif
#else
  return exp2f(x);
#endif
}

// CNOT-ladder index map g (verified in R1-R3).
__device__ __forceinline__ int gperm(int t) {
  int u = t;
#define APPLY(c, tt) u ^= (((u >> (3 - (c))) & 1) << (3 - (tt)));
  APPLY(3, 1) APPLY(2, 0) APPLY(1, 3) APPLY(0, 2)
  APPLY(3, 0) APPLY(2, 3) APPLY(1, 2) APPLY(0, 1)
#undef APPLY
  return u;
}

// ---------------- kernel 1: xwP[b,t,j] = x[b,t,:] @ W_x[:,g(j)] + b_in[g(j)] ----------------

__global__ __launch_bounds__(256) void xw_kernel(
    const float* __restrict__ x, const float* __restrict__ W_in,
    const float* __restrict__ b_in, float* __restrict__ xw) {
  __shared__ __align__(16) float xs[16][132];
  __shared__ float wl[2048];
  __shared__ float bl[16];
  const int tid = threadIdx.x;
  const long r0 = (long)blockIdx.x * 16;
#pragma unroll
  for (int i = 0; i < 8; ++i) {
    int idx = tid + i * 256;
    xs[idx >> 7][idx & 127] = x[(r0 + (idx >> 7)) * 128 + (idx & 127)];
  }
#pragma unroll
  for (int i = 0; i < 8; ++i) {
    int idx = tid + i * 256;
    wl[idx] = W_in[2048 + idx];   // W_x = W_in[128:256, :]
  }
  if (tid < 16) bl[tid] = b_in[tid];
  __syncthreads();
  const int rr = tid >> 4, j = tid & 15;
  const int gj = gperm(j);
  float s = bl[gj];
#pragma unroll
  for (int k4 = 0; k4 < 32; ++k4) {
    float4 v = *reinterpret_cast<const float4*>(&xs[rr][k4 * 4]);
    int kb = k4 * 4;
    s = fmaf(v.x, wl[(kb + 0) * 16 + gj], s);
    s = fmaf(v.y, wl[(kb + 1) * 16 + gj], s);
    s = fmaf(v.z, wl[(kb + 2) * 16 + gj], s);
    s = fmaf(v.w, wl[(kb + 3) * 16 + gj], s);
  }
  xw[(r0 + rr) * 16 + j] = s;
}

// ---------------- kernel 2: fused fwd+bwd recurrence ----------------
// 8 blocks x 1024 threads = 16 independent waves/block, one fwd+bwd batch-row
// pair per wave. 16 waves round-robin onto 4 SIMDs -> 4 waves/SIMD co-resident;
// SMT interleaving fills each wave's dependency stalls (R3 was 1 wave/SIMD at
// ~86% issue, 14% dead). Per-wave code identical to the verified R3 kernel.

__global__ __launch_bounds__(64 * PAIRS_PER_BLOCK, 1) void qbigru_fused(
    const float* __restrict__ W_in,
    const float* __restrict__ W_out,
    const float* __restrict__ b_out,
    const float* __restrict__ thr_f, const float* __restrict__ thr1_f, const float* __restrict__ thu_f,
    const float* __restrict__ thr_b, const float* __restrict__ thr1_b, const float* __restrict__ thu_b,
    const float* __restrict__ xw,
    float* __restrict__ out) {
  const int lane = threadIdx.x & 63;
  const int wid  = threadIdx.x >> 6;
  const int l4   = lane & 15;
  const int b    = blockIdx.x * PAIRS_PER_BLOCK + wid;
  const bool lt2 = (lane >> 4) < 2;

  // xor4-within-row via row_shl:4 / row_shr:4 + probe-derived select (convention-proof).
  const int pshl = dpp_i<0x104>(lane);
  const int sel4 = (pshl == (lane ^ 4)) ? ~0 : 0;
  auto xor4f = [&](float x) {
    int a = dpp_i<0x104>(__float_as_int(x));
    int c = dpp_i<0x114>(__float_as_int(x));
    return __int_as_float((a & sel4) | (c & ~sel4));
  };

  // Select-free reduce-scatter. Input: v[i] = partial of column (i ^ l4).
  // Output: full 64-lane sum for column l4, replicated in every lane.
  auto bfr = [&](const float* v) -> float {
    float w1[8];
#pragma unroll
    for (int j = 0; j < 8; ++j) w1[j] = v[2 * j] + dpp_f<0xB1>(v[2 * j + 1]);   // col bit0 (xor1)
    float w2[4];
#pragma unroll
    for (int j = 0; j < 4; ++j) w2[j] = w1[2 * j] + dpp_f<0x4E>(w1[2 * j + 1]); // col bit1 (xor2)
    float w3[2];
#pragma unroll
    for (int j = 0; j < 2; ++j) w3[j] = w2[j] + dpp_f<0x128>(w2[j + 2]);        // col bit3 (xor8)
    float y0 = w3[0] + xor4f(w3[1]);                                            // col bit2 (xor4)
    return pls32_sum(pls16_sum(y0));
  };

  // +/- butterfly: eb[B](l) = (-1)^{l_B} * sum_s p[s]*(1-2*bit_B(s)); n2 = sum p.
  auto ebf = [&](float p, float& n2, float* eb) {
    float s4 = xor4f(p);
    float P  = p + s4, M2 = p - s4;
    float dP = dpp_f<0x128>(P), dM2 = dpp_f<0x128>(M2);
    float P3 = P + dP, M3 = P - dP; M2 = M2 + dM2;
    float a1 = dpp_f<0x4E>(P3), a2 = dpp_f<0x4E>(M3), a3 = dpp_f<0x4E>(M2);
    float P1 = P3 + a1, M1 = P3 - a1; M3 += a2; M2 += a3;
    float b0_ = dpp_f<0xB1>(P1), b1_ = dpp_f<0xB1>(M1), b3_ = dpp_f<0xB1>(M3), b2_ = dpp_f<0xB1>(M2);
    n2 = P1 + b0_;
    eb[0] = P1 - b0_; eb[1] = M1 + b1_; eb[3] = M3 + b3_; eb[2] = M2 + b2_;
  };

  // ---- per-lane constants ----
  const float* thsA[2]; const float* ths1[2];
  thsA[0] = lt2 ? thr_f : thu_f;  ths1[0] = thr1_f;
  thsA[1] = lt2 ? thr_b : thu_b;  ths1[1] = thr1_b;
  float ch1[2][4], sh1[2][4], ch2[2][4], sh2[2][4];
#pragma unroll
  for (int s = 0; s < 2; ++s) {
#pragma unroll
    for (int i = 0; i < 4; ++i) {
      float a  = 0.5f * thsA[s][i]; ch1[s][i] = cosf(a);  sh1[s][i] = sinf(a);
      float a2 = 0.5f * ths1[s][i]; ch2[s][i] = cosf(a2); sh2[s][i] = sinf(a2);
    }
  }

  // W_h, XOR layout + CNOT perm folded: slot i holds column g(i ^ l4). Lane covers k = lane, lane+64.
  f32x2 w0p[8], w1p[8];
#pragma unroll
  for (int i = 0; i < 8; ++i) {
    int ja = gperm((2 * i) ^ l4), jb = gperm((2 * i + 1) ^ l4);
    f32x2 a, c;
    a.x = W_in[lane * QDIM + ja];        a.y = W_in[lane * QDIM + jb];
    c.x = W_in[(lane + 64) * QDIM + ja]; c.y = W_in[(lane + 64) * QDIM + jb];
    w0p[i] = a; w1p[i] = c;
  }

  // W_out reindexed (wire w = 3-B) with e-butterfly sign correction (-1)^{l_B}.
  float woP0[4], woP1[4];
#pragma unroll
  for (int B = 0; B < 4; ++B) {
    float sgn = ((lane >> B) & 1) ? -1.f : 1.f;
    woP0[B] = W_out[(3 - B) * HID + lane] * sgn;
    woP1[B] = W_out[(3 - B) * HID + lane + 64] * sgn;
  }
  const float L2E = 1.4426950408889634f;
  const float nbc0 = -b_out[lane] * L2E;
  const float nbc1 = -b_out[lane + 64] * L2E;
  const float bc20 = b_out[lane] * (2.f * L2E);
  const float bc21 = b_out[lane + 64] * (2.f * L2E);

  auto dot4 = [](const float* e, const float* w) {
    return fmaf(e[1], w[1], e[0] * w[0]) + fmaf(e[3], w[3], e[2] * w[2]);
  };

#define MVSTAGE(SHUF, CH, SH)  { float Rp = SHUF(Re), Ip = SHUF(Im); \
    Re = fmaf((CH), Re, (SH) * Ip); Im = fmaf((CH), Im, -(SH) * Rp); }

  float h0[2] = {0.f, 0.f}, h1[2] = {0.f, 0.f};
  const float* pxw0 = xw + (long)b * TSEQ * QDIM + l4;                 // fwd
  const float* pxw1 = xw + ((long)b * TSEQ + TSEQ - 1) * QDIM + l4;    // bwd
  float xc[2], xn[2];
  xc[0] = pxw0[0]; pxw0 += QDIM;  xn[0] = pxw0[0]; pxw0 += QDIM;
  xc[1] = pxw1[0]; pxw1 -= QDIM;  xn[1] = pxw1[0]; pxw1 -= QDIM;

  float* po = out + (long)b * TSEQ * HID + lane;

#pragma unroll 1
  for (int t = 0; t < TSEQ; ++t) {
    float xnn0 = pxw0[0]; pxw0 += QDIM;   // prefetch t+2 (ws padded; overrun harmless)
    float xnn1 = pxw1[0]; pxw1 -= QDIM;

    // ---- half 1: y = h@W_h + xw ; VQC1 ; gates r,z ---- (both seqs, independent chains)
    float prb1[2], yv[2];
#pragma unroll
    for (int s = 0; s < 2; ++s) {
      f32x2 hA; hA.x = h0[s]; hA.y = h0[s];
      f32x2 hB; hB.x = h1[s]; hB.y = h1[s];
      float v[16];
#pragma unroll
      for (int i = 0; i < 8; ++i) {
        f32x2 a = hA * w0p[i] + hB * w1p[i];
        v[2 * i] = a.x; v[2 * i + 1] = a.y;
      }
      yv[s] = bfr(v) + xc[s];
      float Re = ch1[s][1] * yv[s];
      float Im = -sh1[s][1] * xor4f(yv[s]);
      MVSTAGE(dpp_f<0x128>, ch1[s][0], sh1[s][0])   // qubit0, d=8
      MVSTAGE(dpp_f<0x4E>,  ch1[s][2], sh1[s][2])   // qubit2, d=2
      MVSTAGE(dpp_f<0xB1>,  ch1[s][3], sh1[s][3])   // qubit3, d=1
      prb1[s] = fmaf(Re, Re, Im * Im);
    }

    float r0[2], r1[2], z0[2], z1[2];
#pragma unroll
    for (int s = 0; s < 2; ++s) {
      float n2, eb[4];
      ebf(prb1[s], n2, eb);
      float inv = rcpf(n2);
      float eo[4];
#pragma unroll
      for (int B = 0; B < 4; ++B) eo[B] = pls32_other(eb[B]);
      float dO0 = dot4(eb, woP0), dO1 = dot4(eb, woP1);
      float dX0 = dot4(eo, woP0), dX1 = dot4(eo, woP1);
      float rd0 = lt2 ? dO0 : dX0, rd1 = lt2 ? dO1 : dX1;
      float zd0 = lt2 ? dX0 : dO0, zd1 = lt2 ? dX1 : dO1;
      float nic = inv * (-L2E);
      r0[s] = rcpf(1.f + ex2(fmaf(rd0, nic, nbc0)));
      r1[s] = rcpf(1.f + ex2(fmaf(rd1, nic, nbc1)));
      z0[s] = rcpf(1.f + ex2(fmaf(zd0, nic, nbc0)));
      z1[s] = rcpf(1.f + ex2(fmaf(zd1, nic, nbc1)));
    }

    // ---- half 2: v1 = (r*h)@W_h + xw ; VQC2 ; candidate h2 ----
    float h20[2], h21[2];
#pragma unroll
    for (int s = 0; s < 2; ++s) {
      float rh0 = r0[s] * h0[s], rh1 = r1[s] * h1[s];
      f32x2 hA; hA.x = rh0; hA.y = rh0;
      f32x2 hB; hB.x = rh1; hB.y = rh1;
      float v[16];
#pragma unroll
      for (int i = 0; i < 8; ++i) {
        f32x2 a = hA * w0p[i] + hB * w1p[i];
        v[2 * i] = a.x; v[2 * i + 1] = a.y;
      }
      float vv = bfr(v) + xc[s];
      float Re = ch2[s][1] * vv;
      float Im = -sh2[s][1] * xor4f(vv);
      MVSTAGE(dpp_f<0x128>, ch2[s][0], sh2[s][0])
      MVSTAGE(dpp_f<0x4E>,  ch2[s][2], sh2[s][2])
      MVSTAGE(dpp_f<0xB1>,  ch2[s][3], sh2[s][3])
      float prb2 = fmaf(Re, Re, Im * Im);
      float n2b, eb2[4];
      ebf(prb2, n2b, eb2);
      float invb = rcpf(n2b);
      float hd0 = dot4(eb2, woP0), hd1 = dot4(eb2, woP1);
      float i2c = invb * (2.f * L2E);
      h20[s] = fmaf(-2.f, rcpf(1.f + ex2(fmaf(hd0, i2c, bc20))), 1.f);
      h21[s] = fmaf(-2.f, rcpf(1.f + ex2(fmaf(hd1, i2c, bc21))), 1.f);
    }

#pragma unroll
    for (int s = 0; s < 2; ++s) {
      h0[s] = fmaf(z0[s], h20[s] - h0[s], h0[s]);
      h1[s] = fmaf(z1[s], h21[s] - h1[s], h1[s]);
    }

    // fwd step t and bwd step t both target out[b,t,:] (reference adds in loop order).
    po[0]  = 0.5f * (h0[0] + h0[1]);
    po[64] = 0.5f * (h1[0] + h1[1]);
    po += HID;

    xc[0] = xn[0]; xn[0] = xnn0;
    xc[1] = xn[1]; xn[1] = xnn1;
  }
#undef MVSTAGE
}

// ---------------- launch ----------------

extern "C" void kernel_launch(void* const* d_in, const int* in_sizes, int n_in,
                              void* d_out, int out_size, void* d_ws, size_t ws_size,
                              hipStream_t stream) {
  const float* x     = (const float*)d_in[0];
  const float* W_in  = (const float*)d_in[1];
  const float* b_in  = (const float*)d_in[2];
  const float* W_out = (const float*)d_in[3];
  const float* b_out = (const float*)d_in[4];
  const float* thr_f  = (const float*)d_in[5];
  const float* thr1_f = (const float*)d_in[6];
  const float* thu_f  = (const float*)d_in[7];
  const float* thr_b  = (const float*)d_in[8];
  const float* thr1_b = (const float*)d_in[9];
  const float* thu_b  = (const float*)d_in[10];
  float* out = (float*)d_out;

  char* ws = (char*)d_ws;
  const size_t PAD = 4096;   // xw prefetch over/under-run guard
  float* xw = (float*)(ws + PAD);

  xw_kernel<<<(NB * TSEQ) / 16, 256, 0, stream>>>(x, W_in, b_in, xw);

  qbigru_fused<<<NB / PAIRS_PER_BLOCK, 64 * PAIRS_PER_BLOCK, 0, stream>>>(
      W_in, W_out, b_out,
      thr_f, thr1_f, thu_f, thr_b, thr1_b, thu_b, xw, out);
}

// Round 5
// 780.798 us; speedup vs baseline: 4.8990x; 4.8990x over previous
//
#include <hip/hip_runtime.h>
#include <hip/hip_bf16.h>

#define TSEQ 1024
#define NB   128
#define HID  128
#define QDIM 16

typedef unsigned int  u32;
typedef unsigned short u16;
typedef float f32x2 __attribute__((ext_vector_type(2)));

// ---------------- cross-lane helpers (wave64) ----------------

template<int CTRL>
__device__ __forceinline__ int dpp_i(int x) {
  return __builtin_amdgcn_update_dpp(0, x, CTRL, 0xF, 0xF, true);
}
template<int CTRL>
__device__ __forceinline__ float dpp_f(float x) {
  return __int_as_float(dpp_i<CTRL>(__float_as_int(x)));
}

#ifdef __has_builtin
#if __has_builtin(__builtin_amdgcn_permlane16_swap) && __has_builtin(__builtin_amdgcn_permlane32_swap)
#define HAS_PLS 1
#endif
#endif
#ifndef HAS_PLS
#define HAS_PLS 0
#endif

__device__ __forceinline__ float pls16_sum(float x) {
#if HAS_PLS
  auto r = __builtin_amdgcn_permlane16_swap(__float_as_uint(x), __float_as_uint(x), false, false);
  return __uint_as_float(r[0]) + __uint_as_float(r[1]);
#else
  return x + __shfl_xor(x, 16, 64);
#endif
}
__device__ __forceinline__ float pls32_sum(float x) {
#if HAS_PLS
  auto r = __builtin_amdgcn_permlane32_swap(__float_as_uint(x), __float_as_uint(x), false, false);
  return __uint_as_float(r[0]) + __uint_as_float(r[1]);
#else
  return x + __shfl_xor(x, 32, 64);
#endif
}
__device__ __forceinline__ float pls32_other(float x) { return pls32_sum(x) - x; }

__device__ __forceinline__ float rcpf(float x) { return __builtin_amdgcn_rcpf(x); }

__device__ __forceinline__ float ex2(float x) {
#if defined(__has_builtin)
#if __has_builtin(__builtin_amdgcn_exp2f)
  return __builtin_amdgcn_exp2f(x);
#else
  return exp2f(x);
#endif
#else
  return exp2f(x);
#endif
}

__device__ __forceinline__ u16 f2bf(float f) {
  u32 u = __float_as_uint(f);
  u32 r = (u + 0x7FFFu + ((u >> 16) & 1u)) >> 16;
  return (u16)r;
}

// CNOT-ladder index map g (verified in R1-R4).
__device__ __forceinline__ int gperm(int t) {
  int u = t;
#define APPLY(c, tt) u ^= (((u >> (3 - (c))) & 1) << (3 - (tt)));
  APPLY(3, 1) APPLY(2, 0) APPLY(1, 3) APPLY(0, 2)
  APPLY(3, 0) APPLY(2, 3) APPLY(1, 2) APPLY(0, 1)
#undef APPLY
  return u;
}

// ---------------- kernel 1: xwP[b,t,j] = x[b,t,:] @ W_x[:,g(j)] + b_in[g(j)] ----------------

__global__ __launch_bounds__(256) void xw_kernel(
    const float* __restrict__ x, const float* __restrict__ W_in,
    const float* __restrict__ b_in, float* __restrict__ xw) {
  __shared__ __align__(16) float xs[16][132];
  __shared__ float wl[2048];
  __shared__ float bl[16];
  const int tid = threadIdx.x;
  const long r0 = (long)blockIdx.x * 16;
#pragma unroll
  for (int i = 0; i < 8; ++i) {
    int idx = tid + i * 256;
    xs[idx >> 7][idx & 127] = x[(r0 + (idx >> 7)) * 128 + (idx & 127)];
  }
#pragma unroll
  for (int i = 0; i < 8; ++i) {
    int idx = tid + i * 256;
    wl[idx] = W_in[2048 + idx];   // W_x = W_in[128:256, :]
  }
  if (tid < 16) bl[tid] = b_in[tid];
  __syncthreads();
  const int rr = tid >> 4, j = tid & 15;
  const int gj = gperm(j);
  float s = bl[gj];
#pragma unroll
  for (int k4 = 0; k4 < 32; ++k4) {
    float4 v = *reinterpret_cast<const float4*>(&xs[rr][k4 * 4]);
    int kb = k4 * 4;
    s = fmaf(v.x, wl[(kb + 0) * 16 + gj], s);
    s = fmaf(v.y, wl[(kb + 1) * 16 + gj], s);
    s = fmaf(v.z, wl[(kb + 2) * 16 + gj], s);
    s = fmaf(v.w, wl[(kb + 3) * 16 + gj], s);
  }
  xw[(r0 + rr) * 16 + j] = s;
}

// ---------------- kernel 2: recurrence. 256 blocks x 1 wave; all-register ----------------
// amdgpu_waves_per_eu(1,2): we run 1 wave/SIMD by design; raise the register
// allocator's budget to 256 VGPRs so the ~100 live values (weights, trig
// tables, butterfly temps) are NOT rematerialized/reloaded every iteration.
// (R2 identical code was squeezed to 48 VGPRs -> ~2x instruction inflation.)

template<bool BF16WS>
__global__ __launch_bounds__(64)
__attribute__((amdgpu_waves_per_eu(1, 2)))
void qbigru_main(
    const float* __restrict__ W_in,
    const float* __restrict__ W_out,
    const float* __restrict__ b_out,
    const float* __restrict__ thr_f, const float* __restrict__ thr1_f, const float* __restrict__ thu_f,
    const float* __restrict__ thr_b, const float* __restrict__ thr1_b, const float* __restrict__ thu_b,
    const float* __restrict__ xw,
    float* __restrict__ out,
    void* __restrict__ bwdws) {
  const int tid = threadIdx.x;
  const int l4  = tid & 15;
  const int dir = blockIdx.x >> 7;
  const int b   = blockIdx.x & 127;
  const bool lt2 = (tid >> 4) < 2;

  // xor4-within-row via row_shl:4 / row_shr:4 + probe-derived select (convention-proof).
  const int pshl = dpp_i<0x104>(tid);
  const int sel4 = (pshl == (tid ^ 4)) ? ~0 : 0;
  auto xor4f = [&](float x) {
    int a = dpp_i<0x104>(__float_as_int(x));
    int c = dpp_i<0x114>(__float_as_int(x));
    return __int_as_float((a & sel4) | (c & ~sel4));
  };

  // Select-free reduce-scatter. Input: v[i] = partial of column (i ^ l4).
  // Output: full 64-lane sum for column l4, replicated in every lane.
  auto bfr = [&](const float* v) -> float {
    float w1[8];
#pragma unroll
    for (int j = 0; j < 8; ++j) w1[j] = v[2 * j] + dpp_f<0xB1>(v[2 * j + 1]);   // col bit0 (xor1)
    float w2[4];
#pragma unroll
    for (int j = 0; j < 4; ++j) w2[j] = w1[2 * j] + dpp_f<0x4E>(w1[2 * j + 1]); // col bit1 (xor2)
    float w3[2];
#pragma unroll
    for (int j = 0; j < 2; ++j) w3[j] = w2[j] + dpp_f<0x128>(w2[j + 2]);        // col bit3 (xor8)
    float y0 = w3[0] + xor4f(w3[1]);                                            // col bit2 (xor4)
    return pls32_sum(pls16_sum(y0));
  };

  // +/- butterfly: eb[B](l) = (-1)^{l_B} * sum_s p[s]*(1-2*bit_B(s)); n2 = sum p.
  auto ebf = [&](float p, float& n2, float* eb) {
    float s4 = xor4f(p);
    float P  = p + s4, M2 = p - s4;
    float dP = dpp_f<0x128>(P), dM2 = dpp_f<0x128>(M2);
    float P3 = P + dP, M3 = P - dP; M2 = M2 + dM2;
    float a1 = dpp_f<0x4E>(P3), a2 = dpp_f<0x4E>(M3), a3 = dpp_f<0x4E>(M2);
    float P1 = P3 + a1, M1 = P3 - a1; M3 += a2; M2 += a3;
    float b0_ = dpp_f<0xB1>(P1), b1_ = dpp_f<0xB1>(M1), b3_ = dpp_f<0xB1>(M3), b2_ = dpp_f<0xB1>(M2);
    n2 = P1 + b0_;
    eb[0] = P1 - b0_; eb[1] = M1 + b1_; eb[3] = M3 + b3_; eb[2] = M2 + b2_;
  };

  // ---- per-lane constants ----
  const float* thr  = dir ? thr_b  : thr_f;
  const float* thr1 = dir ? thr1_b : thr1_f;
  const float* thu  = dir ? thu_b  : thu_f;
  const float* thA  = lt2 ? thr : thu;   // rows 0,1 -> reset VQC; rows 2,3 -> update VQC
  float ch1[4], sh1[4], ch2[4], sh2[4];
#pragma unroll
  for (int i = 0; i < 4; ++i) {
    float a = 0.5f * thA[i];   ch1[i] = cosf(a);  sh1[i] = sinf(a);
    float a2 = 0.5f * thr1[i]; ch2[i] = cosf(a2); sh2[i] = sinf(a2);
  }

  // W_h, XOR layout + CNOT perm folded: slot i holds column g(i ^ l4). Lane covers k = tid, tid+64.
  f32x2 w0p[8], w1p[8];
#pragma unroll
  for (int i = 0; i < 8; ++i) {
    int ja = gperm((2 * i) ^ l4), jb = gperm((2 * i + 1) ^ l4);
    f32x2 a, c;
    a.x = W_in[tid * QDIM + ja];        a.y = W_in[tid * QDIM + jb];
    c.x = W_in[(tid + 64) * QDIM + ja]; c.y = W_in[(tid + 64) * QDIM + jb];
    w0p[i] = a; w1p[i] = c;
  }

  // W_out reindexed (wire w = 3-B) with e-butterfly sign correction (-1)^{l_B}.
  float woP0[4], woP1[4];
#pragma unroll
  for (int B = 0; B < 4; ++B) {
    float sgn = ((tid >> B) & 1) ? -1.f : 1.f;
    woP0[B] = W_out[(3 - B) * HID + tid] * sgn;
    woP1[B] = W_out[(3 - B) * HID + tid + 64] * sgn;
  }
  const float L2E = 1.4426950408889634f;
  const float nbc0 = -b_out[tid] * L2E;
  const float nbc1 = -b_out[tid + 64] * L2E;
  const float bc20 = b_out[tid] * (2.f * L2E);
  const float bc21 = b_out[tid + 64] * (2.f * L2E);

  auto dot4 = [](const float* e, const float* w) {
    return fmaf(e[1], w[1], e[0] * w[0]) + fmaf(e[3], w[3], e[2] * w[2]);
  };

#define MVSTAGE(SHUF, CH, SH)  { float Rp = SHUF(Re), Ip = SHUF(Im); \
    Re = fmaf((CH), Re, (SH) * Ip); Im = fmaf((CH), Im, -(SH) * Rp); }

  float h0 = 0.f, h1 = 0.f;
  const float* pxw = xw + ((long)b * TSEQ + (dir ? TSEQ - 1 : 0)) * QDIM;
  const long xstep = dir ? -QDIM : QDIM;
  float xc = pxw[l4]; pxw += xstep;
  float xn = pxw[l4]; pxw += xstep;

  float* po  = out + (long)b * TSEQ * HID + tid;
  float* pbf = (float*)bwdws + (long)b * TSEQ * HID + tid;
  u16*   pbh = (u16*)bwdws + (long)b * TSEQ * HID + tid;

#pragma unroll 1
  for (int t = 0; t < TSEQ; ++t) {
    float xnn = pxw[l4]; pxw += xstep;   // prefetch t+2 (ws padded; overrun harmless)

    // ---- y = h @ W_h (permuted cols) + xwP ----
    f32x2 hh0; hh0.x = h0; hh0.y = h0;
    f32x2 hh1; hh1.x = h1; hh1.y = h1;
    float v[16];
#pragma unroll
    for (int i = 0; i < 8; ++i) {
      f32x2 a = hh0 * w0p[i] + hh1 * w1p[i];
      v[2 * i] = a.x; v[2 * i + 1] = a.y;
    }
    float yv = bfr(v) + xc;

    // ---- VQC1: 4 RX stages on lane-local complex amp (qubit1/d=4 first, Im==0) ----
    float Re = ch1[1] * yv;
    float Im = -sh1[1] * xor4f(yv);
    MVSTAGE(dpp_f<0x128>, ch1[0], sh1[0])   // qubit0, d=8
    MVSTAGE(dpp_f<0x4E>,  ch1[2], sh1[2])   // qubit2, d=2
    MVSTAGE(dpp_f<0xB1>,  ch1[3], sh1[3])   // qubit3, d=1
    float prb = fmaf(Re, Re, Im * Im);      // probs_raw[col] (own VQC)

    float n2, eb[4];
    ebf(prb, n2, eb);
    float inv = rcpf(n2);
    float eo[4];
#pragma unroll
    for (int B = 0; B < 4; ++B) eo[B] = pls32_other(eb[B]);

    float dO0 = dot4(eb, woP0), dO1 = dot4(eb, woP1);
    float dX0 = dot4(eo, woP0), dX1 = dot4(eo, woP1);
    float rd0 = lt2 ? dO0 : dX0, rd1 = lt2 ? dO1 : dX1;
    float zd0 = lt2 ? dX0 : dO0, zd1 = lt2 ? dX1 : dO1;

    float nic = inv * (-L2E);
    float r0 = rcpf(1.f + ex2(fmaf(rd0, nic, nbc0)));
    float r1 = rcpf(1.f + ex2(fmaf(rd1, nic, nbc1)));
    float z0 = rcpf(1.f + ex2(fmaf(zd0, nic, nbc0)));
    float z1 = rcpf(1.f + ex2(fmaf(zd1, nic, nbc1)));

    // ---- v1 = (r*h) @ W_h + xwP ----
    float rh0 = r0 * h0, rh1 = r1 * h1;
    hh0.x = rh0; hh0.y = rh0;
    hh1.x = rh1; hh1.y = rh1;
#pragma unroll
    for (int i = 0; i < 8; ++i) {
      f32x2 a = hh0 * w0p[i] + hh1 * w1p[i];
      v[2 * i] = a.x; v[2 * i + 1] = a.y;
    }
    float vv = bfr(v) + xc;

    float Re2 = ch2[1] * vv;
    float Im2 = -sh2[1] * xor4f(vv);
    { float& Re = Re2; float& Im = Im2;
      MVSTAGE(dpp_f<0x128>, ch2[0], sh2[0])
      MVSTAGE(dpp_f<0x4E>,  ch2[2], sh2[2])
      MVSTAGE(dpp_f<0xB1>,  ch2[3], sh2[3])
    }
    float prb2 = fmaf(Re2, Re2, Im2 * Im2);

    float n2b, eb2[4];
    ebf(prb2, n2b, eb2);
    float invb = rcpf(n2b);
    float hd0 = dot4(eb2, woP0), hd1 = dot4(eb2, woP1);

    float i2c = invb * (2.f * L2E);
    float h20 = fmaf(-2.f, rcpf(1.f + ex2(fmaf(hd0, i2c, bc20))), 1.f);
    float h21 = fmaf(-2.f, rcpf(1.f + ex2(fmaf(hd1, i2c, bc21))), 1.f);

    float hn0 = fmaf(z0, h20 - h0, h0);
    float hn1 = fmaf(z1, h21 - h1, h1);

    if (dir == 0) {
      po[0]  = 0.5f * hn0;
      po[64] = 0.5f * hn1;
      po += HID;
    } else if (BF16WS) {
      pbh[0]  = f2bf(0.5f * hn0);
      pbh[64] = f2bf(0.5f * hn1);
      pbh += HID;
    } else {
      pbf[0]  = 0.5f * hn0;
      pbf[64] = 0.5f * hn1;
      pbf += HID;
    }

    h0 = hn0; h1 = hn1;
    xc = xn; xn = xnn;
  }
#undef MVSTAGE
}

// ---------------- kernel 3: out += bwd trajectory ----------------

template<bool BF16WS>
__global__ __launch_bounds__(256) void combine_k(float* __restrict__ out,
                                                 const void* __restrict__ bwd, long n4) {
  long i = (long)blockIdx.x * 256 + threadIdx.x;
  const long stride = (long)gridDim.x * 256;
  for (; i < n4; i += stride) {
    float4 o = reinterpret_cast<float4*>(out)[i];
    float ax, ay, az, aw;
    if (BF16WS) {
      ushort4 u = reinterpret_cast<const ushort4*>(bwd)[i];
      ax = __uint_as_float((u32)u.x << 16);
      ay = __uint_as_float((u32)u.y << 16);
      az = __uint_as_float((u32)u.z << 16);
      aw = __uint_as_float((u32)u.w << 16);
    } else {
      float4 a = reinterpret_cast<const float4*>(bwd)[i];
      ax = a.x; ay = a.y; az = a.z; aw = a.w;
    }
    o.x += ax; o.y += ay; o.z += az; o.w += aw;
    reinterpret_cast<float4*>(out)[i] = o;
  }
}

// ---------------- launch ----------------

extern "C" void kernel_launch(void* const* d_in, const int* in_sizes, int n_in,
                              void* d_out, int out_size, void* d_ws, size_t ws_size,
                              hipStream_t stream) {
  const float* x     = (const float*)d_in[0];
  const float* W_in  = (const float*)d_in[1];
  const float* b_in  = (const float*)d_in[2];
  const float* W_out = (const float*)d_in[3];
  const float* b_out = (const float*)d_in[4];
  const float* thr_f  = (const float*)d_in[5];
  const float* thr1_f = (const float*)d_in[6];
  const float* thu_f  = (const float*)d_in[7];
  const float* thr_b  = (const float*)d_in[8];
  const float* thr1_b = (const float*)d_in[9];
  const float* thu_b  = (const float*)d_in[10];
  float* out = (float*)d_out;

  char* ws = (char*)d_ws;
  const size_t PAD = 4096;   // xw prefetch over/under-run guard
  const size_t xw_bytes = (size_t)NB * TSEQ * QDIM * sizeof(float);   // 8 MB
  float* xw = (float*)(ws + PAD);
  void* bwd = (void*)(ws + PAD + xw_bytes + PAD);
  const size_t need_f32 = 2 * PAD + xw_bytes + (size_t)NB * TSEQ * HID * sizeof(float);
  const bool f32ws = (ws_size >= need_f32);

  xw_kernel<<<(NB * TSEQ) / 16, 256, 0, stream>>>(x, W_in, b_in, xw);

  if (f32ws) {
    qbigru_main<false><<<256, 64, 0, stream>>>(W_in, W_out, b_out,
        thr_f, thr1_f, thu_f, thr_b, thr1_b, thu_b, xw, out, bwd);
  } else {
    qbigru_main<true><<<256, 64, 0, stream>>>(W_in, W_out, b_out,
        thr_f, thr1_f, thu_f, thr_b, thr1_b, thu_b, xw, out, bwd);
  }

  const long n4 = (long)NB * TSEQ * HID / 4;
  if (f32ws) combine_k<false><<<2048, 256, 0, stream>>>(out, bwd, n4);
  else       combine_k<true><<<2048, 256, 0, stream>>>(out, bwd, n4);
}

// Round 6
// 701.241 us; speedup vs baseline: 5.4548x; 1.1135x over previous
//
#include <hip/hip_runtime.h>
#include <hip/hip_bf16.h>

#define TSEQ 1024
#define NB   128
#define HID  128
#define QDIM 16

typedef unsigned int  u32;
typedef unsigned short u16;
typedef float f32x2 __attribute__((ext_vector_type(2)));

// ---------------- cross-lane helpers (wave64) ----------------

template<int CTRL>
__device__ __forceinline__ int dpp_i(int x) {
  return __builtin_amdgcn_update_dpp(0, x, CTRL, 0xF, 0xF, true);
}
template<int CTRL>
__device__ __forceinline__ float dpp_f(float x) {
  return __int_as_float(dpp_i<CTRL>(__float_as_int(x)));
}

#ifdef __has_builtin
#if __has_builtin(__builtin_amdgcn_permlane16_swap) && __has_builtin(__builtin_amdgcn_permlane32_swap)
#define HAS_PLS 1
#endif
#endif
#ifndef HAS_PLS
#define HAS_PLS 0
#endif

__device__ __forceinline__ float pls16_sum(float x) {
#if HAS_PLS
  auto r = __builtin_amdgcn_permlane16_swap(__float_as_uint(x), __float_as_uint(x), false, false);
  return __uint_as_float(r[0]) + __uint_as_float(r[1]);
#else
  return x + __shfl_xor(x, 16, 64);
#endif
}
__device__ __forceinline__ float pls32_sum(float x) {
#if HAS_PLS
  auto r = __builtin_amdgcn_permlane32_swap(__float_as_uint(x), __float_as_uint(x), false, false);
  return __uint_as_float(r[0]) + __uint_as_float(r[1]);
#else
  return x + __shfl_xor(x, 32, 64);
#endif
}
__device__ __forceinline__ float pls32_other(float x) { return pls32_sum(x) - x; }

__device__ __forceinline__ float rcpf(float x) { return __builtin_amdgcn_rcpf(x); }

__device__ __forceinline__ float ex2(float x) {
#if defined(__has_builtin)
#if __has_builtin(__builtin_amdgcn_exp2f)
  return __builtin_amdgcn_exp2f(x);
#else
  return exp2f(x);
#endif
#else
  return exp2f(x);
#endif
}

__device__ __forceinline__ u16 f2bf(float f) {
  u32 u = __float_as_uint(f);
  u32 r = (u + 0x7FFFu + ((u >> 16) & 1u)) >> 16;
  return (u16)r;
}

__device__ __forceinline__ f32x2 s2(float x) { f32x2 r; r.x = x; r.y = x; return r; }

// CNOT-ladder index map g (verified in R1-R5).
__device__ __forceinline__ int gperm(int t) {
  int u = t;
#define APPLY(c, tt) u ^= (((u >> (3 - (c))) & 1) << (3 - (tt)));
  APPLY(3, 1) APPLY(2, 0) APPLY(1, 3) APPLY(0, 2)
  APPLY(3, 0) APPLY(2, 3) APPLY(1, 2) APPLY(0, 1)
#undef APPLY
  return u;
}

// ---------------- kernel 1: xwP[b,t,j] = x[b,t,:] @ W_x[:,g(j)] + b_in[g(j)] ----------------

__global__ __launch_bounds__(256) void xw_kernel(
    const float* __restrict__ x, const float* __restrict__ W_in,
    const float* __restrict__ b_in, float* __restrict__ xw) {
  __shared__ __align__(16) float xs[16][132];
  __shared__ float wl[2048];
  __shared__ float bl[16];
  const int tid = threadIdx.x;
  const long r0 = (long)blockIdx.x * 16;
#pragma unroll
  for (int i = 0; i < 8; ++i) {
    int idx = tid + i * 256;
    xs[idx >> 7][idx & 127] = x[(r0 + (idx >> 7)) * 128 + (idx & 127)];
  }
#pragma unroll
  for (int i = 0; i < 8; ++i) {
    int idx = tid + i * 256;
    wl[idx] = W_in[2048 + idx];   // W_x = W_in[128:256, :]
  }
  if (tid < 16) bl[tid] = b_in[tid];
  __syncthreads();
  const int rr = tid >> 4, j = tid & 15;
  const int gj = gperm(j);
  float s = bl[gj];
#pragma unroll
  for (int k4 = 0; k4 < 32; ++k4) {
    float4 v = *reinterpret_cast<const float4*>(&xs[rr][k4 * 4]);
    int kb = k4 * 4;
    s = fmaf(v.x, wl[(kb + 0) * 16 + gj], s);
    s = fmaf(v.y, wl[(kb + 1) * 16 + gj], s);
    s = fmaf(v.z, wl[(kb + 2) * 16 + gj], s);
    s = fmaf(v.w, wl[(kb + 3) * 16 + gj], s);
  }
  xw[(r0 + rr) * 16 + j] = s;
}

// ---------------- kernel 2: recurrence. 256 blocks x 1 wave; all-register ----------------

template<bool BF16WS>
__global__ __launch_bounds__(64)
__attribute__((amdgpu_waves_per_eu(1, 2)))
void qbigru_main(
    const float* __restrict__ W_in,
    const float* __restrict__ W_out,
    const float* __restrict__ b_out,
    const float* __restrict__ thr_f, const float* __restrict__ thr1_f, const float* __restrict__ thu_f,
    const float* __restrict__ thr_b, const float* __restrict__ thr1_b, const float* __restrict__ thu_b,
    const float* __restrict__ xw,
    float* __restrict__ out,
    void* __restrict__ bwdws) {
  const int tid = threadIdx.x;
  const int l4  = tid & 15;
  const int dir = blockIdx.x >> 7;
  const int b   = blockIdx.x & 127;
  const bool lt2 = (tid >> 4) < 2;

  // xor4-within-row via row_shl:4 / row_shr:4 + probe-derived select (convention-proof).
  const int pshl = dpp_i<0x104>(tid);
  const int sel4 = (pshl == (tid ^ 4)) ? ~0 : 0;
  auto xor4f = [&](float x) {
    int a = dpp_i<0x104>(__float_as_int(x));
    int c = dpp_i<0x114>(__float_as_int(x));
    return __int_as_float((a & sel4) | (c & ~sel4));
  };

  // Select-free reduce-scatter. Input: v[i] = partial of column (i ^ l4).
  // Output: full 64-lane sum for column l4, replicated in every lane.
  auto bfr = [&](const float* v) -> float {
    float w1[8];
#pragma unroll
    for (int j = 0; j < 8; ++j) w1[j] = v[2 * j] + dpp_f<0xB1>(v[2 * j + 1]);   // col bit0 (xor1)
    float w2[4];
#pragma unroll
    for (int j = 0; j < 4; ++j) w2[j] = w1[2 * j] + dpp_f<0x4E>(w1[2 * j + 1]); // col bit1 (xor2)
    float w3[2];
#pragma unroll
    for (int j = 0; j < 2; ++j) w3[j] = w2[j] + dpp_f<0x128>(w2[j + 2]);        // col bit3 (xor8)
    float y0 = w3[0] + xor4f(w3[1]);                                            // col bit2 (xor4)
    return pls32_sum(pls16_sum(y0));
  };

  // +/- butterfly: eb[B](l) = (-1)^{l_B} * sum_s p[s]*(1-2*bit_B(s)); n2 = sum p.
  auto ebf = [&](float p, float& n2, float* eb) {
    float s4 = xor4f(p);
    float P  = p + s4, M2 = p - s4;
    float dP = dpp_f<0x128>(P), dM2 = dpp_f<0x128>(M2);
    float P3 = P + dP, M3 = P - dP; M2 = M2 + dM2;
    float a1 = dpp_f<0x4E>(P3), a2 = dpp_f<0x4E>(M3), a3 = dpp_f<0x4E>(M2);
    float P1 = P3 + a1, M1 = P3 - a1; M3 += a2; M2 += a3;
    float b0_ = dpp_f<0xB1>(P1), b1_ = dpp_f<0xB1>(M1), b3_ = dpp_f<0xB1>(M3), b2_ = dpp_f<0xB1>(M2);
    n2 = P1 + b0_;
    eb[0] = P1 - b0_; eb[1] = M1 + b1_; eb[3] = M3 + b3_; eb[2] = M2 + b2_;
  };

  // ---- per-lane constants ----
  const float* thr  = dir ? thr_b  : thr_f;
  const float* thr1 = dir ? thr1_b : thr1_f;
  const float* thu  = dir ? thu_b  : thu_f;
  const float* thA  = lt2 ? thr : thu;   // rows 0,1 -> reset VQC; rows 2,3 -> update VQC
  float ch1[4], sh1[4], ch2[4], sh2[4];
#pragma unroll
  for (int i = 0; i < 4; ++i) {
    float a = 0.5f * thA[i];   ch1[i] = cosf(a);  sh1[i] = sinf(a);
    float a2 = 0.5f * thr1[i]; ch2[i] = cosf(a2); sh2[i] = sinf(a2);
  }

  // W_h, XOR layout + CNOT perm folded: slot i holds column g(i ^ l4). Lane covers k = tid, tid+64.
  f32x2 w0p[8], w1p[8];
#pragma unroll
  for (int i = 0; i < 8; ++i) {
    int ja = gperm((2 * i) ^ l4), jb = gperm((2 * i + 1) ^ l4);
    f32x2 a, c;
    a.x = W_in[tid * QDIM + ja];        a.y = W_in[tid * QDIM + jb];
    c.x = W_in[(tid + 64) * QDIM + ja]; c.y = W_in[(tid + 64) * QDIM + jb];
    w0p[i] = a; w1p[i] = c;
  }

  // W_out pk pairs over (m=tid, m=tid+64), wire w = 3-B, with e-butterfly sign
  // correction (-1)^{l_B}. woPpk = own columns; woPXpk = partner-lane (tid^32)
  // columns (sign uses OWN lane bits: eb carries (-1)^{own l_B}; bits 0-3 of
  // tid and tid^32 are identical anyway).
  const int ptid = tid ^ 32;
  f32x2 woPpk[4], woPXpk[4];
#pragma unroll
  for (int B = 0; B < 4; ++B) {
    float sgn = ((tid >> B) & 1) ? -1.f : 1.f;
    f32x2 a, c;
    a.x = W_out[(3 - B) * HID + tid] * sgn;
    a.y = W_out[(3 - B) * HID + tid + 64] * sgn;
    c.x = W_out[(3 - B) * HID + ptid] * sgn;
    c.y = W_out[(3 - B) * HID + ptid + 64] * sgn;
    woPpk[B] = a; woPXpk[B] = c;
  }
  const float L2E = 1.4426950408889634f;
  f32x2 nbcpk, bc2pk;
  nbcpk.x = -b_out[tid] * L2E;        nbcpk.y = -b_out[tid + 64] * L2E;
  bc2pk.x =  b_out[tid] * (2.f * L2E); bc2pk.y =  b_out[tid + 64] * (2.f * L2E);

  // pk dot over B=0..3 with scalar e's splatted (op_sel splat, no movs expected)
  auto dot4pk = [](const float* e, const f32x2* w) -> f32x2 {
    f32x2 d = s2(e[0]) * w[0];
    d = s2(e[1]) * w[1] + d;
    d = s2(e[2]) * w[2] + d;
    d = s2(e[3]) * w[3] + d;
    return d;
  };

#define MVSTAGE(SHUF, CH, SH)  { float Rp = SHUF(Re), Ip = SHUF(Im); \
    Re = fmaf((CH), Re, (SH) * Ip); Im = fmaf((CH), Im, -(SH) * Rp); }

  f32x2 hpk; hpk.x = 0.f; hpk.y = 0.f;   // h[tid], h[tid+64]
  const float* pxw = xw + ((long)b * TSEQ + (dir ? TSEQ - 1 : 0)) * QDIM;
  const long xstep = dir ? -QDIM : QDIM;
  float xc = pxw[l4]; pxw += xstep;
  float xn = pxw[l4]; pxw += xstep;

  float* po  = out + (long)b * TSEQ * HID + tid;
  float* pbf = (float*)bwdws + (long)b * TSEQ * HID + tid;
  u16*   pbh = (u16*)bwdws + (long)b * TSEQ * HID + tid;

#pragma unroll 1
  for (int t = 0; t < TSEQ; ++t) {
    float xnn = pxw[l4]; pxw += xstep;   // prefetch t+2 (ws padded; overrun harmless)

    // ---- y = h @ W_h (permuted cols) + xwP ----
    f32x2 hh0 = s2(hpk.x);
    f32x2 hh1 = s2(hpk.y);
    float v[16];
#pragma unroll
    for (int i = 0; i < 8; ++i) {
      f32x2 a = hh0 * w0p[i] + hh1 * w1p[i];
      v[2 * i] = a.x; v[2 * i + 1] = a.y;
    }
    float yv = bfr(v) + xc;

    // ---- VQC1: 4 RX stages on lane-local complex amp (qubit1/d=4 first, Im==0) ----
    float Re = ch1[1] * yv;
    float Im = -sh1[1] * xor4f(yv);
    MVSTAGE(dpp_f<0x128>, ch1[0], sh1[0])   // qubit0, d=8
    MVSTAGE(dpp_f<0x4E>,  ch1[2], sh1[2])   // qubit2, d=2
    MVSTAGE(dpp_f<0xB1>,  ch1[3], sh1[3])   // qubit3, d=1
    float prb = fmaf(Re, Re, Im * Im);      // probs_raw[col] (own VQC)

    float n2, eb[4];
    ebf(prb, n2, eb);
    // Both VQCs are unitary: n2 == |y|^2 for either theta set -> share it.
    float inv = rcpf(n2);
    float nic = inv * (-L2E);

    // Own-e dots for own m-pair, and own-e dots for PARTNER's m-pair; one
    // pls32 crossing then delivers the other gate type's dots for our m's.
    f32x2 dO  = dot4pk(eb, woPpk);    // own gate type, m = (tid, tid+64)
    f32x2 dXp = dot4pk(eb, woPXpk);   // own gate type, partner's m-pair
    f32x2 recv;
    recv.x = pls32_other(dXp.x);      // other gate type, our m-pair
    recv.y = pls32_other(dXp.y);
    f32x2 rd, zd;
    rd.x = lt2 ? dO.x : recv.x;  rd.y = lt2 ? dO.y : recv.y;
    zd.x = lt2 ? recv.x : dO.x;  zd.y = lt2 ? recv.y : dO.y;

    f32x2 ra = rd * s2(nic) + nbcpk;
    f32x2 za = zd * s2(nic) + nbcpk;
    float r0 = rcpf(1.f + ex2(ra.x));
    float r1 = rcpf(1.f + ex2(ra.y));
    float z0 = rcpf(1.f + ex2(za.x));
    float z1 = rcpf(1.f + ex2(za.y));

    // ---- v1 = (r*h) @ W_h + xwP ----
    f32x2 rpk; rpk.x = r0; rpk.y = r1;
    f32x2 rh = rpk * hpk;
    hh0 = s2(rh.x);
    hh1 = s2(rh.y);
#pragma unroll
    for (int i = 0; i < 8; ++i) {
      f32x2 a = hh0 * w0p[i] + hh1 * w1p[i];
      v[2 * i] = a.x; v[2 * i + 1] = a.y;
    }
    float vv = bfr(v) + xc;

    float Re2 = ch2[1] * vv;
    float Im2 = -sh2[1] * xor4f(vv);
    { float& Re = Re2; float& Im = Im2;
      MVSTAGE(dpp_f<0x128>, ch2[0], sh2[0])
      MVSTAGE(dpp_f<0x4E>,  ch2[2], sh2[2])
      MVSTAGE(dpp_f<0xB1>,  ch2[3], sh2[3])
    }
    float prb2 = fmaf(Re2, Re2, Im2 * Im2);

    float n2b, eb2[4];
    ebf(prb2, n2b, eb2);
    float invb = rcpf(n2b);
    f32x2 hd = dot4pk(eb2, woPpk);    // all rows share VQC2 -> own columns only
    f32x2 ha = hd * s2(invb * (2.f * L2E)) + bc2pk;
    float h20 = fmaf(-2.f, rcpf(1.f + ex2(ha.x)), 1.f);
    float h21 = fmaf(-2.f, rcpf(1.f + ex2(ha.y)), 1.f);

    f32x2 h2pk; h2pk.x = h20; h2pk.y = h21;
    f32x2 zpk;  zpk.x  = z0;  zpk.y  = z1;
    hpk = zpk * (h2pk - hpk) + hpk;

    f32x2 opk = hpk * s2(0.5f);
    if (dir == 0) {
      po[0]  = opk.x;
      po[64] = opk.y;
      po += HID;
    } else if (BF16WS) {
      pbh[0]  = f2bf(opk.x);
      pbh[64] = f2bf(opk.y);
      pbh += HID;
    } else {
      pbf[0]  = opk.x;
      pbf[64] = opk.y;
      pbf += HID;
    }

    xc = xn; xn = xnn;
  }
#undef MVSTAGE
}

// ---------------- kernel 3: out += bwd trajectory ----------------

template<bool BF16WS>
__global__ __launch_bounds__(256) void combine_k(float* __restrict__ out,
                                                 const void* __restrict__ bwd, long n4) {
  long i = (long)blockIdx.x * 256 + threadIdx.x;
  const long stride = (long)gridDim.x * 256;
  for (; i < n4; i += stride) {
    float4 o = reinterpret_cast<float4*>(out)[i];
    float ax, ay, az, aw;
    if (BF16WS) {
      ushort4 u = reinterpret_cast<const ushort4*>(bwd)[i];
      ax = __uint_as_float((u32)u.x << 16);
      ay = __uint_as_float((u32)u.y << 16);
      az = __uint_as_float((u32)u.z << 16);
      aw = __uint_as_float((u32)u.w << 16);
    } else {
      float4 a = reinterpret_cast<const float4*>(bwd)[i];
      ax = a.x; ay = a.y; az = a.z; aw = a.w;
    }
    o.x += ax; o.y += ay; o.z += az; o.w += aw;
    reinterpret_cast<float4*>(out)[i] = o;
  }
}

// ---------------- launch ----------------

extern "C" void kernel_launch(void* const* d_in, const int* in_sizes, int n_in,
                              void* d_out, int out_size, void* d_ws, size_t ws_size,
                              hipStream_t stream) {
  const float* x     = (const float*)d_in[0];
  const float* W_in  = (const float*)d_in[1];
  const float* b_in  = (const float*)d_in[2];
  const float* W_out = (const float*)d_in[3];
  const float* b_out = (const float*)d_in[4];
  const float* thr_f  = (const float*)d_in[5];
  const float* thr1_f = (const float*)d_in[6];
  const float* thu_f  = (const float*)d_in[7];
  const float* thr_b  = (const float*)d_in[8];
  const float* thr1_b = (const float*)d_in[9];
  const float* thu_b  = (const float*)d_in[10];
  float* out = (float*)d_out;

  char* ws = (char*)d_ws;
  const size_t PAD = 4096;   // xw prefetch over/under-run guard
  const size_t xw_bytes = (size_t)NB * TSEQ * QDIM * sizeof(float);   // 8 MB
  float* xw = (float*)(ws + PAD);
  void* bwd = (void*)(ws + PAD + xw_bytes + PAD);
  const size_t need_f32 = 2 * PAD + xw_bytes + (size_t)NB * TSEQ * HID * sizeof(float);
  const bool f32ws = (ws_size >= need_f32);

  xw_kernel<<<(NB * TSEQ) / 16, 256, 0, stream>>>(x, W_in, b_in, xw);

  if (f32ws) {
    qbigru_main<false><<<256, 64, 0, stream>>>(W_in, W_out, b_out,
        thr_f, thr1_f, thu_f, thr_b, thr1_b, thu_b, xw, out, bwd);
  } else {
    qbigru_main<true><<<256, 64, 0, stream>>>(W_in, W_out, b_out,
        thr_f, thr1_f, thu_f, thr_b, thr1_b, thu_b, xw, out, bwd);
  }

  const long n4 = (long)NB * TSEQ * HID / 4;
  if (f32ws) combine_k<false><<<2048, 256, 0, stream>>>(out, bwd, n4);
  else       combine_k<true><<<2048, 256, 0, stream>>>(out, bwd, n4);
}